// Round 16
// baseline (1855.491 us; speedup 1.0000x reference)
//
#include <hip/hip_runtime.h>
#include <hip/hip_bf16.h>
#include <math.h>

#define VAR_N 4
#define LEVELS 17
#define NCELLS 56
#define PRED_N 12
#define TSTEPS 4096
#define TROWS (TSTEPS + PRED_N)
#define DT 0.1f
#define RPB 8
#define LOG2E 1.44269504088896340736f
#define TB 8

static __device__ __forceinline__ float rl(float x, int lane) {
    return __int_as_float(__builtin_amdgcn_readlane(__float_as_int(x), lane));
}
static __device__ __forceinline__ float rcpf(float x) {
    return __builtin_amdgcn_rcpf(x);
}
// Full-wave rotate-left-by-1 (GFX9 DPP wave_rol1 = 0x134): lane j <- lane (j+1)&63
static __device__ __forceinline__ float rotl1(float x) {
    return __int_as_float(__builtin_amdgcn_mov_dpp(__float_as_int(x), 0x134, 0xF, 0xF, false));
}

// ---------------------------------------------------------------------------
// Kernel 1: preproc encoder (68->68 x5) fused with gprep (proven, unchanged).
// ---------------------------------------------------------------------------
__global__ void pre_g_kernel(const float* __restrict__ x,
                             const float* __restrict__ w1, const float* __restrict__ b1,
                             const float* __restrict__ w2, const float* __restrict__ b2,
                             const float* __restrict__ w3, const float* __restrict__ b3,
                             const float* __restrict__ w4, const float* __restrict__ b4,
                             const float* __restrict__ w5, const float* __restrict__ b5,
                             const float* __restrict__ wx, const float* __restrict__ bvec,
                             float* __restrict__ g) {
    __shared__ float lds[2 * RPB * 68];
    float* bufA = lds;
    float* bufB = lds + RPB * 68;
    const int r0 = blockIdx.x * RPB;
    const int tid = threadIdx.x;

    for (int idx = tid; idx < RPB * 68; idx += 256)
        bufA[idx] = x[(size_t)r0 * 68 + idx];
    __syncthreads();

    const float* Ws[5] = {w1, w2, w3, w4, w5};
    const float* Bs[5] = {b1, b2, b3, b4, b5};
    for (int L = 0; L < 5; ++L) {
        const float* __restrict__ W = Ws[L];
        const bool act = (L < 4);
        if (tid < 68) {
            const int j = tid;
            float acc[RPB];
            float bj = Bs[L][j];
#pragma unroll
            for (int r = 0; r < RPB; ++r) acc[r] = bj;
            for (int k = 0; k + 4 <= 68; k += 4) {
                float w0v = W[(k + 0) * 68 + j];
                float w1v = W[(k + 1) * 68 + j];
                float w2v = W[(k + 2) * 68 + j];
                float w3v = W[(k + 3) * 68 + j];
#pragma unroll
                for (int r = 0; r < RPB; ++r) {
                    const float4 hx = *(const float4*)(bufA + r * 68 + k);
                    acc[r] = fmaf(hx.x, w0v, fmaf(hx.y, w1v,
                              fmaf(hx.z, w2v, fmaf(hx.w, w3v, acc[r]))));
                }
            }
#pragma unroll
            for (int r = 0; r < RPB; ++r)
                bufB[r * 68 + j] = act ? fmaxf(acc[r], 0.f) : acc[r];
        }
        __syncthreads();
        float* t = bufA; bufA = bufB; bufB = t;
    }

    for (int idx = tid; idx < RPB * 4 * NCELLS; idx += 256) {
        int r = idx / 224;
        int rem = idx - r * 224;
        int q = rem / NCELLS;
        int j = rem - q * NCELLS;
        int gr = r0 + r;
        int v = gr >> 10;
        int trow = ((gr & 1023) << 2) + q;
        const float* arow = bufA + r * 68 + q * LEVELS;
        float acc = bvec[v * NCELLS + j];
#pragma unroll
        for (int l = 0; l < LEVELS; ++l)
            acc = fmaf(arow[l], wx[(v * LEVELS + l) * NCELLS + j], acc);
        g[((size_t)(v * NCELLS + j)) * TSTEPS + trow] = acc * LOG2E;
    }
}

// ---------------------------------------------------------------------------
// Kernel 2: sequential LTC scan — NEW: systolic DPP rotation. The h
// broadcast runs on the VALU via 63 wave_rol1 rotations (no DS ops in the
// hot loop). Lane j at iter i holds h_{(j+i)&63}; weight wrot[i] =
// LOG2E*wh[(j+i)&63][j], zero for pad slots (garbage*0 stays finite).
// ---------------------------------------------------------------------------
__global__ void __launch_bounds__(64, 1) scan_kernel(
    const float* __restrict__ g, const float* __restrict__ wh,
    const float* __restrict__ a, const float* __restrict__ tau,
    const float* __restrict__ wx, const float* __restrict__ wout,
    const float* __restrict__ bout, const float* __restrict__ b,
    float* __restrict__ H) {
    const int v = blockIdx.x;
    const int lane = threadIdx.x;
    const bool active = lane < NCELLS;
    const int j = active ? lane : (NCELLS - 1);

    // wrot[i]: weight for the value arriving after i left-rotations
    float wrot[64];
#pragma unroll
    for (int i = 0; i < 64; ++i) {
        int k = (lane + i) & 63;
        wrot[i] = (active && k < NCELLS)
                      ? wh[((size_t)v * NCELLS + k) * NCELLS + lane] * LOG2E
                      : 0.f;
    }
    const float alpha = active ? DT * a[v * NCELLS + lane] : 0.f;
    const float cden = active ? 1.f + DT / (tau[v * NCELLS + lane] + 0.5f) : 1.f;

    const float4* __restrict__ gv4 = (const float4*)(g + ((size_t)v * NCELLS + j) * TSTEPS);
    float* __restrict__ hp = H + (size_t)v * TROWS * NCELLS + lane;

    auto cell = [&](float h, float gcur) -> float {
        float hr = h;
        float z0 = gcur, z1 = 0.f, z2a = 0.f, z3 = 0.f;
#pragma unroll
        for (int i = 0; i < 64; ++i) {
            float w = wrot[i];
            if ((i & 3) == 0) z0 = fmaf(hr, w, z0);
            else if ((i & 3) == 1) z1 = fmaf(hr, w, z1);
            else if ((i & 3) == 2) z2a = fmaf(hr, w, z2a);
            else z3 = fmaf(hr, w, z3);
            if (i < 63) hr = rotl1(hr);
        }
        float z2 = (z0 + z1) + (z2a + z3);            // log2 domain
        float zc = fmaxf(z2, -80.f);                  // keep e finite
        float e = __builtin_amdgcn_exp2f(-zc);
        float t1 = 1.f + e;
        float num = fmaf(h, t1, alpha);
        float den = fmaf(cden, t1, DT);
        return num * rcpf(den);
    };

    float h = 0.f;
    float4 gq = gv4[0];
    for (int tq = 0; tq < TSTEPS / 4; ++tq) {
        float4 gn = gq;
        if (tq + 1 < TSTEPS / 4) gn = gv4[tq + 1];   // prefetch ~4 steps ahead
        h = cell(h, gq.x); if (active) hp[0 * NCELLS] = h;
        h = cell(h, gq.y); if (active) hp[1 * NCELLS] = h;
        h = cell(h, gq.z); if (active) hp[2 * NCELLS] = h;
        h = cell(h, gq.w); if (active) hp[3 * NCELLS] = h;
        hp += 4 * NCELLS;
        gq = gn;
    }

    // ---- autoregressive pred phase (12 steps) ----
    float wxcol[LEVELS];
#pragma unroll
    for (int l = 0; l < LEVELS; ++l)
        wxcol[l] = active ? wx[(v * LEVELS + l) * NCELLS + lane] * LOG2E : 0.f;
    float wtc[NCELLS];  // lane l (<17) holds wout[:, l]
#pragma unroll
    for (int jj = 0; jj < NCELLS; ++jj)
        wtc[jj] = (lane < LEVELS) ? wout[((size_t)v * NCELLS + jj) * LEVELS + lane] : 0.f;
    const float bj = active ? b[v * NCELLS + lane] * LOG2E : 0.f;
    const float boutl = (lane < LEVELS) ? bout[v * LEVELS + lane] : 0.f;

    float vv = boutl;
#pragma unroll
    for (int jj = 0; jj < NCELLS; ++jj) vv = fmaf(rl(h, jj), wtc[jj], vv);

    for (int i = 0; i < PRED_N; ++i) {
        float z2 = bj;
#pragma unroll
        for (int l = 0; l < LEVELS; ++l) z2 = fmaf(rl(vv, l), wxcol[l], z2);
        float hr = h;
#pragma unroll
        for (int q = 0; q < 64; ++q) {
            z2 = fmaf(hr, wrot[q], z2);
            if (q < 63) hr = rotl1(hr);
        }
        float zc = fmaxf(z2, -80.f);
        float e = __builtin_amdgcn_exp2f(-zc);
        float t1 = 1.f + e;
        h = fmaf(h, t1, alpha) * rcpf(fmaf(cden, t1, DT));
        if (active) hp[0] = h;     // H row TSTEPS+i
        hp += NCELLS;
        vv = boutl;
#pragma unroll
        for (int jj = 0; jj < NCELLS; ++jj) vv = fmaf(rl(h, jj), wtc[jj], vv);
    }
}

// ---------------------------------------------------------------------------
// Kernel 3: proj + c1 + c2, 256 threads, TB=8 (R15, unchanged).
// ---------------------------------------------------------------------------
__global__ void __launch_bounds__(256) c1c2_kernel(
    const float* __restrict__ H,
    const float* __restrict__ wout, const float* __restrict__ bout,
    const float* __restrict__ c1w1, const float* __restrict__ c1b1,
    const float* __restrict__ c1w2, const float* __restrict__ c1b2,
    const float* __restrict__ c1w3, const float* __restrict__ c1b3,
    const float* __restrict__ c1w4, const float* __restrict__ c1b4,
    const float* __restrict__ c1w5, const float* __restrict__ c1b5,
    const float* __restrict__ c2w1, const float* __restrict__ c2b1,
    const float* __restrict__ c2w2, const float* __restrict__ c2b2,
    const float* __restrict__ c2w3, const float* __restrict__ c2b3,
    const float* __restrict__ c2w4, const float* __restrict__ c2b4,
    const float* __restrict__ c2w5, const float* __restrict__ c2b5,
    float* __restrict__ out) {
    __shared__ __align__(16) float sH[32 * 56];
    __shared__ __align__(16) float nA[32 * 20];
    __shared__ __align__(16) float nB[32 * 20];
    __shared__ __align__(16) float bY[TB * 272];
    __shared__ __align__(16) float bZ[TB * 272];
    const int t0 = blockIdx.x * TB;
    const int tid = threadIdx.x;

    for (int idx = tid; idx < 32 * 56; idx += 256) {
        int row = idx / 56, jj = idx - (idx / 56) * 56;
        int tq = row >> 2, v = row & 3;
        int t = t0 + tq;
        sH[idx] = (t < TROWS) ? H[((size_t)v * TROWS + t) * 56 + jj] : 0.f;
    }
    __syncthreads();

    if (tid < 136) {
        int l = tid % 17;
        int rg = tid / 17;
        int v = rg & 3, th = rg >> 2;
        float acc[4];
        float bl = bout[v * 17 + l];
#pragma unroll
        for (int q = 0; q < 4; ++q) acc[q] = bl;
        for (int k = 0; k < 56; k += 4) {
            float w0 = wout[(v * 56 + k + 0) * 17 + l];
            float w1 = wout[(v * 56 + k + 1) * 17 + l];
            float w2 = wout[(v * 56 + k + 2) * 17 + l];
            float w3 = wout[(v * 56 + k + 3) * 17 + l];
#pragma unroll
            for (int q = 0; q < 4; ++q) {
                const float4 hx = *(const float4*)(sH + ((th * 4 + q) * 4 + v) * 56 + k);
                acc[q] = fmaf(hx.x, w0, fmaf(hx.y, w1, fmaf(hx.z, w2, fmaf(hx.w, w3, acc[q]))));
            }
        }
#pragma unroll
        for (int q = 0; q < 4; ++q) nA[((th * 4 + q) * 4 + v) * 20 + l] = acc[q];
    }
    __syncthreads();

#pragma unroll
    for (int LL = 0; LL < 2; ++LL) {
        const float* W = LL ? c1w2 : c1w1;
        const float* B = LL ? c1b2 : c1b1;
        const float* in = LL ? nB : nA;
        float* ob = LL ? nA : nB;
        if (tid < 136) {
            int l = tid % 17;
            int rg = tid / 17;
            float acc[4];
            float bl = B[l];
#pragma unroll
            for (int q = 0; q < 4; ++q) acc[q] = bl;
            for (int k = 0; k + 4 <= 17; k += 4) {
                float w0 = W[(k + 0) * 17 + l], w1 = W[(k + 1) * 17 + l];
                float w2 = W[(k + 2) * 17 + l], w3 = W[(k + 3) * 17 + l];
#pragma unroll
                for (int q = 0; q < 4; ++q) {
                    const float4 hx = *(const float4*)(in + (rg * 4 + q) * 20 + k);
                    acc[q] = fmaf(hx.x, w0, fmaf(hx.y, w1, fmaf(hx.z, w2, fmaf(hx.w, w3, acc[q]))));
                }
            }
            float w16 = W[16 * 17 + l];
#pragma unroll
            for (int q = 0; q < 4; ++q)
                ob[(rg * 4 + q) * 20 + l] = fmaxf(fmaf(in[(rg * 4 + q) * 20 + 16], w16, acc[q]), 0.f);
        }
        __syncthreads();
    }

    if (tid < 136) {
        int j = tid % 68;
        int rg = tid / 68;
        float acc[16];
        float bj = c1b3[j];
#pragma unroll
        for (int r = 0; r < 16; ++r) acc[r] = bj;
        for (int k = 0; k + 4 <= 17; k += 4) {
            float w0 = c1w3[(k + 0) * 68 + j], w1 = c1w3[(k + 1) * 68 + j];
            float w2 = c1w3[(k + 2) * 68 + j], w3 = c1w3[(k + 3) * 68 + j];
#pragma unroll
            for (int r = 0; r < 16; ++r) {
                const float4 hx = *(const float4*)(nA + (rg * 16 + r) * 20 + k);
                acc[r] = fmaf(hx.x, w0, fmaf(hx.y, w1, fmaf(hx.z, w2, fmaf(hx.w, w3, acc[r]))));
            }
        }
        float w16 = c1w3[16 * 68 + j];
#pragma unroll
        for (int r = 0; r < 16; ++r)
            bY[(rg * 16 + r) * 68 + j] = fmaxf(fmaf(nA[(rg * 16 + r) * 20 + 16], w16, acc[r]), 0.f);
    }
    __syncthreads();

#pragma unroll
    for (int LL = 0; LL < 2; ++LL) {
        const float* W = LL ? c1w5 : c1w4;
        const float* B = LL ? c1b5 : c1b4;
        const float* in = LL ? bZ : bY;
        float* ob = LL ? bY : bZ;
        if (tid < 136) {
            int j = tid % 68;
            int rg = tid / 68;
            float acc[16];
            float bj = B[j];
#pragma unroll
            for (int r = 0; r < 16; ++r) acc[r] = bj;
            for (int k = 0; k < 68; k += 4) {
                float w0 = W[(k + 0) * 68 + j], w1 = W[(k + 1) * 68 + j];
                float w2 = W[(k + 2) * 68 + j], w3 = W[(k + 3) * 68 + j];
#pragma unroll
                for (int r = 0; r < 16; ++r) {
                    const float4 hx = *(const float4*)(in + (rg * 16 + r) * 68 + k);
                    acc[r] = fmaf(hx.x, w0, fmaf(hx.y, w1, fmaf(hx.z, w2, fmaf(hx.w, w3, acc[r]))));
                }
            }
#pragma unroll
            for (int r = 0; r < 16; ++r)
                ob[(rg * 16 + r) * 68 + j] = fmaxf(acc[r], 0.f);
        }
        __syncthreads();
    }

#pragma unroll
    for (int LL = 0; LL < 2; ++LL) {
        const float* W = LL ? c2w2 : c2w1;
        const float* B = LL ? c2b2 : c2b1;
        const float* in = LL ? bZ : bY;
        float* ob = LL ? bY : bZ;
        if (tid < 136) {
            int j = 2 * tid;
            float acc0[TB], acc1[TB];
            float b0 = B[j], b1 = B[j + 1];
#pragma unroll
            for (int r = 0; r < TB; ++r) { acc0[r] = b0; acc1[r] = b1; }
            for (int k = 0; k < 272; k += 4) {
                float2 w0 = *(const float2*)(W + (size_t)(k + 0) * 272 + j);
                float2 w1 = *(const float2*)(W + (size_t)(k + 1) * 272 + j);
                float2 w2 = *(const float2*)(W + (size_t)(k + 2) * 272 + j);
                float2 w3 = *(const float2*)(W + (size_t)(k + 3) * 272 + j);
#pragma unroll
                for (int r = 0; r < TB; ++r) {
                    const float4 hx = *(const float4*)(in + r * 272 + k);
                    acc0[r] = fmaf(hx.x, w0.x, fmaf(hx.y, w1.x, fmaf(hx.z, w2.x, fmaf(hx.w, w3.x, acc0[r]))));
                    acc1[r] = fmaf(hx.x, w0.y, fmaf(hx.y, w1.y, fmaf(hx.z, w2.y, fmaf(hx.w, w3.y, acc1[r]))));
                }
            }
#pragma unroll
            for (int r = 0; r < TB; ++r) {
                ob[r * 272 + j] = fmaxf(acc0[r], 0.f);
                ob[r * 272 + j + 1] = fmaxf(acc1[r], 0.f);
            }
        }
        __syncthreads();
    }

    if (tid < 136) {
        int j = tid % 68;
        int rg = tid / 68;
        float acc[4];
        float bj = c2b3[j];
#pragma unroll
        for (int r = 0; r < 4; ++r) acc[r] = bj;
        for (int k = 0; k < 272; k += 4) {
            float w0 = c2w3[(size_t)(k + 0) * 68 + j], w1 = c2w3[(size_t)(k + 1) * 68 + j];
            float w2 = c2w3[(size_t)(k + 2) * 68 + j], w3 = c2w3[(size_t)(k + 3) * 68 + j];
#pragma unroll
            for (int r = 0; r < 4; ++r) {
                const float4 hx = *(const float4*)(bY + (rg * 4 + r) * 272 + k);
                acc[r] = fmaf(hx.x, w0, fmaf(hx.y, w1, fmaf(hx.z, w2, fmaf(hx.w, w3, acc[r]))));
            }
        }
#pragma unroll
        for (int r = 0; r < 4; ++r)
            bZ[(rg * 4 + r) * 68 + j] = fmaxf(acc[r], 0.f);
    }
    __syncthreads();

#pragma unroll
    for (int LL = 0; LL < 2; ++LL) {
        const float* W = LL ? c2w5 : c2w4;
        const float* B = LL ? c2b5 : c2b4;
        const float* in = LL ? bY : bZ;
        float* ob = LL ? bZ : bY;
        const bool act = (LL == 0);
        if (tid < 136) {
            int j = tid % 68;
            int rg = tid / 68;
            float acc[4];
            float bj = B[j];
#pragma unroll
            for (int r = 0; r < 4; ++r) acc[r] = bj;
            for (int k = 0; k < 68; k += 4) {
                float w0 = W[(k + 0) * 68 + j], w1 = W[(k + 1) * 68 + j];
                float w2 = W[(k + 2) * 68 + j], w3 = W[(k + 3) * 68 + j];
#pragma unroll
                for (int r = 0; r < 4; ++r) {
                    const float4 hx = *(const float4*)(in + (rg * 4 + r) * 68 + k);
                    acc[r] = fmaf(hx.x, w0, fmaf(hx.y, w1, fmaf(hx.z, w2, fmaf(hx.w, w3, acc[r]))));
                }
            }
#pragma unroll
            for (int r = 0; r < 4; ++r)
                ob[(rg * 4 + r) * 68 + j] = act ? fmaxf(acc[r], 0.f) : acc[r];
        }
        __syncthreads();
    }

    for (int idx = tid; idx < TB * 68; idx += 256) {
        int r = idx / 68, c = idx - (idx / 68) * 68;
        int t = t0 + r;
        if (t < TROWS) out[(size_t)t * 68 + c] = bZ[r * 68 + c];
    }
}

// ---------------------------------------------------------------------------
extern "C" void kernel_launch(void* const* d_in, const int* in_sizes, int n_in,
                              void* d_out, int out_size, void* d_ws, size_t ws_size,
                              hipStream_t stream) {
    const float* x = (const float*)d_in[0];
    const float* pw[5] = {(const float*)d_in[1], (const float*)d_in[3], (const float*)d_in[5],
                          (const float*)d_in[7], (const float*)d_in[9]};
    const float* pb[5] = {(const float*)d_in[2], (const float*)d_in[4], (const float*)d_in[6],
                          (const float*)d_in[8], (const float*)d_in[10]};
    const float* c1w[5] = {(const float*)d_in[11], (const float*)d_in[13], (const float*)d_in[15],
                           (const float*)d_in[17], (const float*)d_in[19]};
    const float* c1b[5] = {(const float*)d_in[12], (const float*)d_in[14], (const float*)d_in[16],
                           (const float*)d_in[18], (const float*)d_in[20]};
    const float* c2w[5] = {(const float*)d_in[21], (const float*)d_in[23], (const float*)d_in[25],
                           (const float*)d_in[27], (const float*)d_in[29]};
    const float* c2b[5] = {(const float*)d_in[22], (const float*)d_in[24], (const float*)d_in[26],
                           (const float*)d_in[28], (const float*)d_in[30]};
    const float* ltc_wx = (const float*)d_in[31];
    const float* ltc_wh = (const float*)d_in[32];
    const float* ltc_b = (const float*)d_in[33];
    const float* ltc_a = (const float*)d_in[34];
    const float* ltc_tau = (const float*)d_in[35];
    const float* ltc_wout = (const float*)d_in[36];
    const float* ltc_bout = (const float*)d_in[37];

    float* ws = (float*)d_ws;
    float* g = ws;                         // 4*56*4096 = 917504 (transposed, LOG2E-scaled)
    float* H = g + 917504;                 // 4*4108*56 = 920192 (raw h, incl. pred rows)
    float* out = (float*)d_out;            // 4108*68

    // 1) preproc encoder + gprep fused
    pre_g_kernel<<<TSTEPS / RPB, 256, 0, stream>>>(
        x, pw[0], pb[0], pw[1], pb[1], pw[2], pb[2], pw[3], pb[3], pw[4], pb[4],
        ltc_wx, ltc_b, g);

    // 2) sequential LTC scan -> raw H (systolic DPP rotation, no DS)
    scan_kernel<<<VAR_N, 64, 0, stream>>>(g, ltc_wh, ltc_a, ltc_tau, ltc_wx,
                                          ltc_wout, ltc_bout, ltc_b, H);

    // 3) proj + c1 + c2 fused
    c1c2_kernel<<<(TROWS + TB - 1) / TB, 256, 0, stream>>>(
        H, ltc_wout, ltc_bout,
        c1w[0], c1b[0], c1w[1], c1b[1], c1w[2], c1b[2], c1w[3], c1b[3], c1w[4], c1b[4],
        c2w[0], c2b[0], c2w[1], c2b[1], c2w[2], c2b[2], c2w[3], c2b[3], c2w[4], c2b[4],
        out);
}